// Round 1
// baseline (546.880 us; speedup 1.0000x reference)
//
#include <hip/hip_runtime.h>

typedef unsigned short u16;
typedef __attribute__((ext_vector_type(8))) short short8;
typedef __attribute__((ext_vector_type(4))) float f32x4;

#define NTOK 343
#define NPAD 352
#define DIMC 512
#define HEADS_ 16
#define HD 32
#define BATCH 128
#define MROWS 43904   // 128*343
#define TBL 117649    // 343*343

__device__ __forceinline__ u16 f2bf(float f) {
  unsigned u = __builtin_bit_cast(unsigned, f);
  unsigned r = (u + 0x7fffu + ((u >> 16) & 1u)) >> 16;
  return (u16)r;
}

__global__ void cvt_f32_bf16_k(const float* __restrict__ in, u16* __restrict__ out, int n4) {
  int i = blockIdx.x * blockDim.x + threadIdx.x;
  int st = gridDim.x * blockDim.x;
  for (; i < n4; i += st) {
    float4 v = reinterpret_cast<const float4*>(in)[i];
    ushort4 o;
    o.x = f2bf(v.x); o.y = f2bf(v.y); o.z = f2bf(v.z); o.w = f2bf(v.w);
    reinterpret_cast<ushort4*>(out)[i] = o;
  }
}

__global__ void bias_pre_k(const float* __restrict__ table, const int* __restrict__ idx,
                           float* __restrict__ bias) {
  int t = blockIdx.x * 256 + threadIdx.x;
  if (t >= TBL) return;
  int id = idx[t];
#pragma unroll
  for (int h = 0; h < HEADS_; ++h) bias[h * TBL + t] = table[id * HEADS_ + h];
}

#define GLD16(gptr, lptr)                                                        \
  __builtin_amdgcn_global_load_lds(                                              \
      (const __attribute__((address_space(1))) void*)(const void*)(gptr),        \
      (__attribute__((address_space(3))) void*)(void*)(lptr), 16, 0, 0)

// C = A @ B^T (+bias).  A: [M][K] bf16, B: [N][K] bf16 (K-contiguous).
// EPI 0: qkv epilogue (bias add, scale cols<512, bf16 out). EPI 1: proj (bias, f32 out).
template <int EPI>
__global__ __launch_bounds__(256) void gemm_bt_k(const u16* __restrict__ A,
                                                 const u16* __restrict__ B,
                                                 const float* __restrict__ bias,
                                                 void* __restrict__ C, int N, int K) {
  const int NBL = N >> 7;
  int bid = blockIdx.x;
  int mb = bid / NBL, nb = bid % NBL;
  __shared__ __align__(16) u16 As[128 * 64];
  __shared__ __align__(16) u16 Bs[128 * 64];
  int tid = threadIdx.x;
  int w = tid >> 6, l = tid & 63;
  int wr = w >> 1, wc = w & 1;
  f32x4 acc[4][4];
#pragma unroll
  for (int i = 0; i < 4; i++)
#pragma unroll
    for (int j = 0; j < 4; j++) acc[i][j] = (f32x4){0.f, 0.f, 0.f, 0.f};

  const int l8r = l >> 3, l8c = l & 7;
  const u16* Abase = A + (size_t)(mb * 128 + w * 32 + l8r) * K + l8c * 8;
  const u16* Bbase = B + (size_t)(nb * 128 + w * 32 + l8r) * K + l8c * 8;
  u16* AsW = As + (w * 32) * 64;
  u16* BsW = Bs + (w * 32) * 64;

  int KT = K >> 6;
  for (int kt = 0; kt < KT; ++kt) {
#pragma unroll
    for (int i4 = 0; i4 < 4; ++i4) {
      GLD16(Abase + kt * 64 + (size_t)(i4 * 8) * K, AsW + i4 * 512 + l * 8);
      GLD16(Bbase + kt * 64 + (size_t)(i4 * 8) * K, BsW + i4 * 512 + l * 8);
    }
    __syncthreads();
#pragma unroll
    for (int kk = 0; kk < 2; ++kk) {
      short8 af[4], bf[4];
#pragma unroll
      for (int i = 0; i < 4; i++)
        af[i] = *reinterpret_cast<const short8*>(As + (wr * 64 + i * 16 + (l & 15)) * 64 +
                                                 kk * 32 + (l >> 4) * 8);
#pragma unroll
      for (int j = 0; j < 4; j++)
        bf[j] = *reinterpret_cast<const short8*>(Bs + (wc * 64 + j * 16 + (l & 15)) * 64 +
                                                 kk * 32 + (l >> 4) * 8);
#pragma unroll
      for (int i = 0; i < 4; i++)
#pragma unroll
        for (int j = 0; j < 4; j++)
          acc[i][j] = __builtin_amdgcn_mfma_f32_16x16x32_bf16(af[i], bf[j], acc[i][j], 0, 0, 0);
    }
    __syncthreads();
  }
  int r0 = mb * 128 + wr * 64 + (l >> 4) * 4;
  int c0 = nb * 128 + wc * 64 + (l & 15);
#pragma unroll
  for (int j = 0; j < 4; j++) {
    int col = c0 + j * 16;
    float bv = bias[col];
#pragma unroll
    for (int i = 0; i < 4; i++) {
#pragma unroll
      for (int r = 0; r < 4; r++) {
        int row = r0 + i * 16 + r;
        float v = acc[i][j][r] + bv;
        if (EPI == 0) {
          if (col < 512) v *= 0.17677669529663687f;  // hd^-0.5 (applied after bias, per ref)
          ((u16*)C)[(size_t)row * N + col] = f2bf(v);
        } else {
          ((float*)C)[(size_t)row * N + col] = v;
        }
      }
    }
  }
}

// One block per (b,h). qkv: [43904][1536] bf16 (q scaled already). out: [43904][512] bf16.
__global__ __launch_bounds__(256) void attn_k(const u16* __restrict__ qkv,
                                              const float* __restrict__ biasArr,
                                              u16* __restrict__ outA) {
  int b = blockIdx.x >> 4;
  int h = blockIdx.x & 15;
  __shared__ __align__(16) u16 qS[NPAD * 40];      // rows padded to 40 (80B, odd*16B stride)
  __shared__ __align__(16) u16 kS[NPAD * 40];
  __shared__ __align__(16) u16 vT[32 * 360];       // v transposed [d][j], 720B rows
  __shared__ __align__(16) u16 pS[4][16 * 360];    // per-wave P tile
  int tid = threadIdx.x;

  for (int idx = tid; idx < NPAD * 4; idx += 256) {
    int row = idx >> 2, seg = idx & 3;
    uint4 vq = {0, 0, 0, 0}, vk = {0, 0, 0, 0};
    if (row < NTOK) {
      size_t base = (size_t)(b * NTOK + row) * 1536 + h * 32 + seg * 8;
      vq = *reinterpret_cast<const uint4*>(qkv + base);
      vk = *reinterpret_cast<const uint4*>(qkv + base + 512);
    }
    *reinterpret_cast<uint4*>(qS + row * 40 + seg * 8) = vq;
    *reinterpret_cast<uint4*>(kS + row * 40 + seg * 8) = vk;
  }
  for (int idx = tid; idx < NTOK * 4; idx += 256) {
    int row = idx >> 2, seg = idx & 3;
    size_t base = (size_t)(b * NTOK + row) * 1536 + 1024 + h * 32 + seg * 8;
    uint4 vv = *reinterpret_cast<const uint4*>(qkv + base);
    const u16* e = reinterpret_cast<const u16*>(&vv);
#pragma unroll
    for (int t = 0; t < 8; ++t) vT[(seg * 8 + t) * 360 + row] = e[t];
  }
  for (int idx = tid; idx < 32 * 9; idx += 256) vT[(idx / 9) * 360 + NTOK + (idx % 9)] = 0;
  __syncthreads();

  int w = tid >> 6, l = tid & 63;
  u16* myP = pS[w];
  const int cl = l & 15, q4 = l >> 4;
  const f32x4 z4 = (f32x4){0.f, 0.f, 0.f, 0.f};
  for (int tq = w; tq < 22; tq += 4) {
    short8 aq = *reinterpret_cast<const short8*>(qS + (tq * 16 + cl) * 40 + q4 * 8);
    f32x4 S[22];
#pragma unroll
    for (int nt = 0; nt < 22; ++nt) {
      short8 bk = *reinterpret_cast<const short8*>(kS + (nt * 16 + cl) * 40 + q4 * 8);
      S[nt] = __builtin_amdgcn_mfma_f32_16x16x32_bf16(aq, bk, z4, 0, 0, 0);
    }
    float mx[4] = {-3e38f, -3e38f, -3e38f, -3e38f};
#pragma unroll
    for (int nt = 0; nt < 22; ++nt) {
      int colg = nt * 16 + cl;
#pragma unroll
      for (int r = 0; r < 4; ++r) {
        int qrow = tq * 16 + q4 * 4 + r;
        float v;
        if (colg < NTOK) {
          float bb = (qrow < NTOK) ? biasArr[h * TBL + qrow * NTOK + colg] : 0.f;
          v = S[nt][r] + bb;
        } else
          v = -1e30f;
        S[nt][r] = v;
        mx[r] = fmaxf(mx[r], v);
      }
    }
#pragma unroll
    for (int off = 1; off < 16; off <<= 1)
#pragma unroll
      for (int r = 0; r < 4; ++r) mx[r] = fmaxf(mx[r], __shfl_xor(mx[r], off));
    float sm[4] = {0.f, 0.f, 0.f, 0.f};
#pragma unroll
    for (int nt = 0; nt < 22; ++nt)
#pragma unroll
      for (int r = 0; r < 4; ++r) {
        float e = __expf(S[nt][r] - mx[r]);
        S[nt][r] = e;
        sm[r] += e;
      }
#pragma unroll
    for (int off = 1; off < 16; off <<= 1)
#pragma unroll
      for (int r = 0; r < 4; ++r) sm[r] += __shfl_xor(sm[r], off);
    float inv[4];
#pragma unroll
    for (int r = 0; r < 4; ++r) inv[r] = 1.0f / sm[r];
#pragma unroll
    for (int nt = 0; nt < 22; ++nt) {
      int colg = nt * 16 + cl;
#pragma unroll
      for (int r = 0; r < 4; ++r) myP[(q4 * 4 + r) * 360 + colg] = f2bf(S[nt][r] * inv[r]);
    }
    f32x4 O[2];
    O[0] = z4; O[1] = z4;
#pragma unroll
    for (int kt2 = 0; kt2 < 11; ++kt2) {
      short8 ap = *reinterpret_cast<const short8*>(myP + cl * 360 + kt2 * 32 + q4 * 8);
#pragma unroll
      for (int nv = 0; nv < 2; ++nv) {
        short8 bv = *reinterpret_cast<const short8*>(vT + (nv * 16 + cl) * 360 + kt2 * 32 + q4 * 8);
        O[nv] = __builtin_amdgcn_mfma_f32_16x16x32_bf16(ap, bv, O[nv], 0, 0, 0);
      }
    }
#pragma unroll
    for (int nv = 0; nv < 2; ++nv)
#pragma unroll
      for (int r = 0; r < 4; ++r) {
        int qrow = tq * 16 + q4 * 4 + r;
        if (qrow < NTOK)
          outA[(size_t)(b * NTOK + qrow) * 512 + h * 32 + nv * 16 + cl] = f2bf(O[nv][r]);
      }
  }
}

extern "C" void kernel_launch(void* const* d_in, const int* in_sizes, int n_in,
                              void* d_out, int out_size, void* d_ws, size_t ws_size,
                              hipStream_t stream) {
  const float* x      = (const float*)d_in[0];
  // d_in[1] = q_global: unused by reference
  const float* qkv_w  = (const float*)d_in[2];
  const float* qkv_b  = (const float*)d_in[3];
  const float* table  = (const float*)d_in[4];
  const float* proj_w = (const float*)d_in[5];
  const float* proj_b = (const float*)d_in[6];
  const int*   relidx = (const int*)d_in[7];

  char* ws = (char*)d_ws;
  u16*   x_bf  = (u16*)(ws);                 // 44,957,696 B (reused as attn-out)
  u16*   qw_bf = (u16*)(ws + 44957696);      //  1,572,864 B
  u16*   pw_bf = (u16*)(ws + 46530560);      //    524,288 B
  u16*   qkv_o = (u16*)(ws + 47054848);      // 134,873,088 B
  float* biasA = (float*)(ws + 181927936);   //  7,529,536 B  (total ~189.5 MB)

  cvt_f32_bf16_k<<<2048, 256, 0, stream>>>(x, x_bf, (BATCH * NTOK * DIMC) / 4);
  cvt_f32_bf16_k<<<768, 256, 0, stream>>>(qkv_w, qw_bf, (3 * DIMC * DIMC) / 4);
  cvt_f32_bf16_k<<<256, 256, 0, stream>>>(proj_w, pw_bf, (DIMC * DIMC) / 4);
  bias_pre_k<<<(TBL + 255) / 256, 256, 0, stream>>>(table, relidx, biasA);

  gemm_bt_k<0><<<343 * 12, 256, 0, stream>>>(x_bf, qw_bf, qkv_b, qkv_o, 1536, 512);
  attn_k<<<BATCH * HEADS_, 256, 0, stream>>>(qkv_o, biasA, x_bf);
  gemm_bt_k<1><<<343 * 4, 256, 0, stream>>>(x_bf, pw_bf, proj_b, d_out, 512, 512);
}

// Round 2
// 347.121 us; speedup vs baseline: 1.5755x; 1.5755x over previous
//
#include <hip/hip_runtime.h>

typedef unsigned short u16;
typedef __attribute__((ext_vector_type(8))) short short8;
typedef __attribute__((ext_vector_type(4))) float f32x4;

#define NTOK 343
#define NPAD 352
#define DIMC 512
#define HEADS_ 16
#define HD 32
#define BATCH 128
#define MROWS 43904   // 128*343
#define TBL 117649    // 343*343

__device__ __forceinline__ u16 f2bf(float f) {
  unsigned u = __builtin_bit_cast(unsigned, f);
  unsigned r = (u + 0x7fffu + ((u >> 16) & 1u)) >> 16;
  return (u16)r;
}
__device__ __forceinline__ float bf2f(u16 x) {
  return __builtin_bit_cast(float, ((unsigned)x) << 16);
}

__global__ void cvt_f32_bf16_k(const float* __restrict__ in, u16* __restrict__ out, int n4) {
  int i = blockIdx.x * blockDim.x + threadIdx.x;
  int st = gridDim.x * blockDim.x;
  for (; i < n4; i += st) {
    float4 v = reinterpret_cast<const float4*>(in)[i];
    ushort4 o;
    o.x = f2bf(v.x); o.y = f2bf(v.y); o.z = f2bf(v.z); o.w = f2bf(v.w);
    reinterpret_cast<ushort4*>(out)[i] = o;
  }
}

// biasB[(((h*22 + nt)*88 + qg)*16 + cl)*4 + r] = bf16 bias(h, q=qg*4+r, col=nt*16+cl), 0 if OOR.
// One 8B store per thread; in attn each lane reads its 4 r-values as one short4.
__global__ void bias_pre_k(const float* __restrict__ table, const int* __restrict__ idx,
                           u16* __restrict__ biasB) {
  int t = blockIdx.x * 256 + threadIdx.x;
  if (t >= HEADS_ * 22 * 88 * 16) return;
  int cl = t & 15;
  int qg = (t >> 4) % 88;
  int nt = ((t >> 4) / 88) % 22;
  int h = (t >> 4) / (88 * 22);
  int col = nt * 16 + cl;
  ushort4 o = {0, 0, 0, 0};
  u16* oe = (u16*)&o;
  if (col < NTOK) {
#pragma unroll
    for (int r = 0; r < 4; ++r) {
      int q = qg * 4 + r;
      if (q < NTOK) oe[r] = f2bf(table[idx[q * NTOK + col] * HEADS_ + h]);
    }
  }
  *reinterpret_cast<ushort4*>(biasB + (size_t)t * 4) = o;
}

#define GLD16(gptr, lptr)                                                        \
  __builtin_amdgcn_global_load_lds(                                              \
      (const __attribute__((address_space(1))) void*)(const void*)(gptr),        \
      (__attribute__((address_space(3))) void*)(void*)(lptr), 16, 0, 0)

// C = A @ B^T (+bias).  A: [M][K] bf16, B: [N][K] bf16 (K-contiguous).
// EPI 0: qkv epilogue (bias add, scale cols<512, bf16 out). EPI 1: proj (bias, f32 out).
template <int EPI>
__global__ __launch_bounds__(256) void gemm_bt_k(const u16* __restrict__ A,
                                                 const u16* __restrict__ B,
                                                 const float* __restrict__ bias,
                                                 void* __restrict__ C, int N, int K) {
  const int NBL = N >> 7;
  int bid = blockIdx.x;
  int mb = bid / NBL, nb = bid % NBL;
  __shared__ __align__(16) u16 As[128 * 64];
  __shared__ __align__(16) u16 Bs[128 * 64];
  int tid = threadIdx.x;
  int w = tid >> 6, l = tid & 63;
  int wr = w >> 1, wc = w & 1;
  f32x4 acc[4][4];
#pragma unroll
  for (int i = 0; i < 4; i++)
#pragma unroll
    for (int j = 0; j < 4; j++) acc[i][j] = (f32x4){0.f, 0.f, 0.f, 0.f};

  const int l8r = l >> 3, l8c = l & 7;
  const u16* Abase = A + (size_t)(mb * 128 + w * 32 + l8r) * K + l8c * 8;
  const u16* Bbase = B + (size_t)(nb * 128 + w * 32 + l8r) * K + l8c * 8;
  u16* AsW = As + (w * 32) * 64;
  u16* BsW = Bs + (w * 32) * 64;

  int KT = K >> 6;
  for (int kt = 0; kt < KT; ++kt) {
#pragma unroll
    for (int i4 = 0; i4 < 4; ++i4) {
      GLD16(Abase + kt * 64 + (size_t)(i4 * 8) * K, AsW + i4 * 512 + l * 8);
      GLD16(Bbase + kt * 64 + (size_t)(i4 * 8) * K, BsW + i4 * 512 + l * 8);
    }
    __syncthreads();
#pragma unroll
    for (int kk = 0; kk < 2; ++kk) {
      short8 af[4], bf[4];
#pragma unroll
      for (int i = 0; i < 4; i++)
        af[i] = *reinterpret_cast<const short8*>(As + (wr * 64 + i * 16 + (l & 15)) * 64 +
                                                 kk * 32 + (l >> 4) * 8);
#pragma unroll
      for (int j = 0; j < 4; j++)
        bf[j] = *reinterpret_cast<const short8*>(Bs + (wc * 64 + j * 16 + (l & 15)) * 64 +
                                                 kk * 32 + (l >> 4) * 8);
#pragma unroll
      for (int i = 0; i < 4; i++)
#pragma unroll
        for (int j = 0; j < 4; j++)
          acc[i][j] = __builtin_amdgcn_mfma_f32_16x16x32_bf16(af[i], bf[j], acc[i][j], 0, 0, 0);
    }
    __syncthreads();
  }
  int r0 = mb * 128 + wr * 64 + (l >> 4) * 4;
  int c0 = nb * 128 + wc * 64 + (l & 15);
#pragma unroll
  for (int j = 0; j < 4; j++) {
    int col = c0 + j * 16;
    float bv = bias[col];
#pragma unroll
    for (int i = 0; i < 4; i++) {
#pragma unroll
      for (int r = 0; r < 4; r++) {
        int row = r0 + i * 16 + r;
        float v = acc[i][j][r] + bv;
        if (EPI == 0) {
          if (col < 512) v *= 0.17677669529663687f;  // hd^-0.5 (applied after bias, per ref)
          ((u16*)C)[(size_t)row * N + col] = f2bf(v);
        } else {
          ((float*)C)[(size_t)row * N + col] = v;
        }
      }
    }
  }
}

// One block per (b,h). XCD-swizzled so each XCD owns 2 heads (bias L2-resident).
// LDS 76.8 KB -> 2 blocks/CU. Q read direct from global; PV in 2 chunks (192+160 cols).
__global__ __launch_bounds__(256, 2) void attn_k(const u16* __restrict__ qkv,
                                                 const u16* __restrict__ biasB,
                                                 u16* __restrict__ outA) {
  int p = blockIdx.x;
  int j = p >> 3;
  int h = 2 * (p & 7) + (j >> 7);
  int b = j & 127;
  __shared__ __align__(16) u16 kS[NPAD * 40];     // 28,160 B (80 B rows = 5x16B, odd)
  __shared__ __align__(16) u16 vT[32 * 360];      // 23,040 B (v transposed [d][j])
  __shared__ __align__(16) u16 pS[4][16 * 200];   // 25,600 B (per-wave P, 400 B rows)
  int tid = threadIdx.x;

  for (int idx = tid; idx < NPAD * 4; idx += 256) {
    int row = idx >> 2, seg = idx & 3;
    uint4 vk = {0, 0, 0, 0};
    if (row < NTOK)
      vk = *reinterpret_cast<const uint4*>(qkv + (size_t)(b * NTOK + row) * 1536 + 512 +
                                           h * 32 + seg * 8);
    *reinterpret_cast<uint4*>(kS + row * 40 + seg * 8) = vk;
  }
  for (int idx = tid; idx < NTOK * 4; idx += 256) {
    int row = idx >> 2, seg = idx & 3;
    size_t base = (size_t)(b * NTOK + row) * 1536 + 1024 + h * 32 + seg * 8;
    uint4 vv = *reinterpret_cast<const uint4*>(qkv + base);
    const u16* e = reinterpret_cast<const u16*>(&vv);
#pragma unroll
    for (int t = 0; t < 8; ++t) vT[(seg * 8 + t) * 360 + row] = e[t];
  }
  for (int idx = tid; idx < 32 * 9; idx += 256) vT[(idx / 9) * 360 + NTOK + (idx % 9)] = 0;
  __syncthreads();

  int w = tid >> 6, l = tid & 63;
  u16* myP = pS[w];
  const int cl = l & 15, q4 = l >> 4;
  const f32x4 z4 = (f32x4){0.f, 0.f, 0.f, 0.f};
  for (int tq = w; tq < 22; tq += 4) {
    // Q fragment direct from global (row = tq*16+cl, elems q4*8..+7)
    short8 aq = (short8){0, 0, 0, 0, 0, 0, 0, 0};
    {
      int qrow = tq * 16 + cl;
      if (qrow < NTOK)
        aq = *reinterpret_cast<const short8*>(qkv + (size_t)(b * NTOK + qrow) * 1536 + h * 32 +
                                              q4 * 8);
    }
    // bias prefetch: one 8B load per nt (4 r-values packed)
    ushort4 bb4[22];
    {
      const u16* bbase = biasB + ((size_t)(h * 22) * 88 + (tq * 4 + q4)) * 64 + cl * 4;
#pragma unroll
      for (int nt = 0; nt < 22; ++nt)
        bb4[nt] = *reinterpret_cast<const ushort4*>(bbase + (size_t)nt * 88 * 64);
    }
    f32x4 S[22];
#pragma unroll
    for (int nt = 0; nt < 22; ++nt) {
      short8 bk = *reinterpret_cast<const short8*>(kS + (nt * 16 + cl) * 40 + q4 * 8);
      S[nt] = __builtin_amdgcn_mfma_f32_16x16x32_bf16(aq, bk, z4, 0, 0, 0);
    }
    float mx[4] = {-3e38f, -3e38f, -3e38f, -3e38f};
#pragma unroll
    for (int nt = 0; nt < 22; ++nt) {
      int colg = nt * 16 + cl;
      const u16* be = (const u16*)&bb4[nt];
#pragma unroll
      for (int r = 0; r < 4; ++r) {
        float v = (colg < NTOK) ? (S[nt][r] + bf2f(be[r])) : -1e30f;
        S[nt][r] = v;
        mx[r] = fmaxf(mx[r], v);
      }
    }
#pragma unroll
    for (int off = 1; off < 16; off <<= 1)
#pragma unroll
      for (int r = 0; r < 4; ++r) mx[r] = fmaxf(mx[r], __shfl_xor(mx[r], off));
    float sm[4] = {0.f, 0.f, 0.f, 0.f};
#pragma unroll
    for (int nt = 0; nt < 22; ++nt)
#pragma unroll
      for (int r = 0; r < 4; ++r) {
        float e = __expf(S[nt][r] - mx[r]);
        S[nt][r] = e;
        sm[r] += e;
      }
#pragma unroll
    for (int off = 1; off < 16; off <<= 1)
#pragma unroll
      for (int r = 0; r < 4; ++r) sm[r] += __shfl_xor(sm[r], off);
    float inv[4];
#pragma unroll
    for (int r = 0; r < 4; ++r) inv[r] = 1.0f / sm[r];

    f32x4 O[2];
    O[0] = z4; O[1] = z4;
    // ---- chunk 0: nt 0..11 (k cols 0..191) ----
    asm volatile("" ::: "memory");  // keep P writes after prior-iter PV reads (DS is in-order per wave)
#pragma unroll
    for (int nt = 0; nt < 12; ++nt)
#pragma unroll
      for (int r = 0; r < 4; ++r)
        myP[(q4 * 4 + r) * 200 + nt * 16 + cl] = f2bf(S[nt][r] * inv[r]);
#pragma unroll
    for (int kt2 = 0; kt2 < 6; ++kt2) {
      short8 ap = *reinterpret_cast<const short8*>(myP + cl * 200 + kt2 * 32 + q4 * 8);
#pragma unroll
      for (int nv = 0; nv < 2; ++nv) {
        short8 bv =
            *reinterpret_cast<const short8*>(vT + (nv * 16 + cl) * 360 + kt2 * 32 + q4 * 8);
        O[nv] = __builtin_amdgcn_mfma_f32_16x16x32_bf16(ap, bv, O[nv], 0, 0, 0);
      }
    }
    // ---- chunk 1: nt 12..21 (k cols 192..351) ----
    asm volatile("" ::: "memory");
#pragma unroll
    for (int nt = 12; nt < 22; ++nt)
#pragma unroll
      for (int r = 0; r < 4; ++r)
        myP[(q4 * 4 + r) * 200 + (nt - 12) * 16 + cl] = f2bf(S[nt][r] * inv[r]);
#pragma unroll
    for (int kt2 = 0; kt2 < 5; ++kt2) {
      short8 ap = *reinterpret_cast<const short8*>(myP + cl * 200 + kt2 * 32 + q4 * 8);
#pragma unroll
      for (int nv = 0; nv < 2; ++nv) {
        short8 bv = *reinterpret_cast<const short8*>(vT + (nv * 16 + cl) * 360 + 192 +
                                                     kt2 * 32 + q4 * 8);
        O[nv] = __builtin_amdgcn_mfma_f32_16x16x32_bf16(ap, bv, O[nv], 0, 0, 0);
      }
    }
#pragma unroll
    for (int nv = 0; nv < 2; ++nv)
#pragma unroll
      for (int r = 0; r < 4; ++r) {
        int qrow = tq * 16 + q4 * 4 + r;
        if (qrow < NTOK)
          outA[(size_t)(b * NTOK + qrow) * 512 + h * 32 + nv * 16 + cl] = f2bf(O[nv][r]);
      }
  }
}

extern "C" void kernel_launch(void* const* d_in, const int* in_sizes, int n_in,
                              void* d_out, int out_size, void* d_ws, size_t ws_size,
                              hipStream_t stream) {
  const float* x      = (const float*)d_in[0];
  // d_in[1] = q_global: unused by reference
  const float* qkv_w  = (const float*)d_in[2];
  const float* qkv_b  = (const float*)d_in[3];
  const float* table  = (const float*)d_in[4];
  const float* proj_w = (const float*)d_in[5];
  const float* proj_b = (const float*)d_in[6];
  const int*   relidx = (const int*)d_in[7];

  char* ws = (char*)d_ws;
  u16*   x_bf  = (u16*)(ws);                 // 44,957,696 B (reused as attn-out)
  u16*   qw_bf = (u16*)(ws + 44957696);      //  1,572,864 B
  u16*   pw_bf = (u16*)(ws + 46530560);      //    524,288 B
  u16*   qkv_o = (u16*)(ws + 47054848);      // 134,873,088 B
  u16*   biasB = (u16*)(ws + 181927936);     //  3,964,928 B (16*22*88*64 u16)

  cvt_f32_bf16_k<<<2048, 256, 0, stream>>>(x, x_bf, (BATCH * NTOK * DIMC) / 4);
  cvt_f32_bf16_k<<<768, 256, 0, stream>>>(qkv_w, qw_bf, (3 * DIMC * DIMC) / 4);
  cvt_f32_bf16_k<<<256, 256, 0, stream>>>(proj_w, pw_bf, (DIMC * DIMC) / 4);
  bias_pre_k<<<(HEADS_ * 22 * 88 * 16 + 255) / 256, 256, 0, stream>>>(table, relidx, biasB);

  gemm_bt_k<0><<<343 * 12, 256, 0, stream>>>(x_bf, qw_bf, qkv_b, qkv_o, 1536, 512);
  attn_k<<<BATCH * HEADS_, 256, 0, stream>>>(qkv_o, biasB, x_bf);
  gemm_bt_k<1><<<343 * 4, 256, 0, stream>>>(x_bf, pw_bf, proj_b, d_out, 512, 512);
}